// Round 10
// baseline (733.750 us; speedup 1.0000x reference)
//
#include <hip/hip_runtime.h>
#include <hip/hip_bf16.h>

// Problem constants (B,S,D,H,E,K = 16,1024,1024,256,8,3)
#define BB 16
#define SS 1024
#define DD 1024
#define HH 256
#define EE 8
// GEMM: M = B*S = 16384, N = D = 1024, K = D = 1024

typedef __attribute__((ext_vector_type(8))) short bf16x8;
typedef __attribute__((ext_vector_type(4))) float f32x4;

static __device__ __forceinline__ ushort f2bf(float f) {
    union { float f; unsigned u; } in;
    in.f = f;
    unsigned u = in.u;
    u += 0x7fffu + ((u >> 16) & 1u);   // round-to-nearest-even
    return (ushort)(u >> 16);
}

#define GLOAD16(gp, lp)                                                          \
    __builtin_amdgcn_global_load_lds(                                            \
        (const __attribute__((address_space(1))) void*)(gp),                     \
        (__attribute__((address_space(3))) void*)(lp), 16, 0, 0)

// ---------------------------------------------------------------- convert x -> bf16
__global__ __launch_bounds__(256) void convert_x_kernel(
    const float* __restrict__ x, ushort* __restrict__ xb)
{
    const size_t n4 = (size_t)BB * SS * DD / 4;   // 4,194,304 float4
    const f32x4* x4 = (const f32x4*)x;
    for (size_t i = (size_t)blockIdx.x * 256 + threadIdx.x; i < n4;
         i += (size_t)gridDim.x * 256) {
        f32x4 v = x4[i];
        ushort4 o;
        o.x = f2bf(v.x); o.y = f2bf(v.y); o.z = f2bf(v.z); o.w = f2bf(v.w);
        ((ushort4*)xb)[i] = o;
    }
}

// ------------------------------------------------- transpose+convert Wg -> WgT bf16
// Wg is [d][e] row-major fp32; WgT is [e][d] bf16.
__global__ __launch_bounds__(256) void transpose_wg_kernel(
    const float* __restrict__ Wg, ushort* __restrict__ WgT)
{
    __shared__ float tile[32][33];
    const int bx = blockIdx.x * 32;   // e base
    const int by = blockIdx.y * 32;   // d base
    const int tx = threadIdx.x & 31;
    const int ty = threadIdx.x >> 5;  // 0..7
    #pragma unroll
    for (int r = ty; r < 32; r += 8)
        tile[r][tx] = Wg[(size_t)(by + r) * DD + bx + tx];
    __syncthreads();
    #pragma unroll
    for (int r = ty; r < 32; r += 8)
        WgT[(size_t)(bx + r) * DD + by + tx] = f2bf(tile[tx][r]);
}

// ------------------------------------------------------------- fused gate GEMM
// gated[m][n] = x[m][n] * sigmoid( (x_bf16 @ Wg_bf16)[m][n] + bg[n] )
// m97-style 128x128 tile, BK=64, 4 waves (2x2), 16x16x32 bf16 MFMA,
// global_load_lds width=16 staging, 2-barrier loop, XCD-chunked swizzle (T1),
// fused pooled-sum epilogue (shfl_xor reduce + atomicAdd).
// UNCHANGED again: theory holds it at ~80 us; if total stays ~715 after the
// broadcast fix, the 8-phase 256^2 port is the next (and last) lever.
__global__ __launch_bounds__(256) void gemm_gate_kernel(
    const ushort* __restrict__ Abf,   // x bf16 [M][K]
    const ushort* __restrict__ BTbf,  // WgT bf16 [N][K]
    const float* __restrict__ xf,     // x fp32 [M][N]  (K==N==1024)
    const float* __restrict__ bg,     // [N]
    float* __restrict__ gated,        // [M][N]
    float* __restrict__ pooled)       // [B][D] sums over S (caller memsets 0)
{
    __shared__ ushort As[128 * 64];
    __shared__ ushort Bs[128 * 64];
    const int tid  = threadIdx.x;
    const int lane = tid & 63;
    const int w    = tid >> 6;        // wave 0..3

    // T1: XCD-chunked bijective swizzle. nwg=1024, 8 XCDs, 128 blocks each.
    const int bid = blockIdx.x;                    // 1D grid of 1024
    const int swz = (bid & 7) * 128 + (bid >> 3);
    const int m0 = (swz >> 3) * 128;               // 128 m-panels
    const int n0 = (swz & 7) * 128;                // 8 n-panels
    const int K = 1024, N = 1024;

    f32x4 acc[4][4];
    #pragma unroll
    for (int i = 0; i < 4; ++i)
        #pragma unroll
        for (int j = 0; j < 4; ++j)
            acc[i][j] = (f32x4){0.f, 0.f, 0.f, 0.f};

    const int srow = (lane >> 3);      // 0..7
    const int scol = (lane & 7) * 8;   // k element offset (8 bf16 = 16B)

    for (int k0 = 0; k0 < K; k0 += 64) {
        __syncthreads();   // previous iter's LDS reads done
        #pragma unroll
        for (int c = 0; c < 4; ++c) {
            const int row = w * 32 + c * 8 + srow;
            GLOAD16(Abf + (size_t)(m0 + row) * K + k0 + scol,
                    (char*)As + w * 4096 + c * 1024 + lane * 16);
        }
        #pragma unroll
        for (int c = 0; c < 4; ++c) {
            const int row = w * 32 + c * 8 + srow;
            GLOAD16(BTbf + (size_t)(n0 + row) * K + k0 + scol,
                    (char*)Bs + w * 4096 + c * 1024 + lane * 16);
        }
        asm volatile("s_waitcnt vmcnt(0)" ::: "memory");
        __syncthreads();

        const int rbase = lane & 15;
        const int kb    = (lane >> 4) * 8;
        const int wr = (w >> 1) * 64;
        const int wc = (w & 1) * 64;
        #pragma unroll
        for (int ks = 0; ks < 2; ++ks) {
            bf16x8 af[4], bfr[4];
            #pragma unroll
            for (int i = 0; i < 4; ++i)
                af[i] = *(const bf16x8*)(As + (wr + i * 16 + rbase) * 64 + ks * 32 + kb);
            #pragma unroll
            for (int j = 0; j < 4; ++j)
                bfr[j] = *(const bf16x8*)(Bs + (wc + j * 16 + rbase) * 64 + ks * 32 + kb);
            #pragma unroll
            for (int i = 0; i < 4; ++i)
                #pragma unroll
                for (int j = 0; j < 4; ++j)
                    acc[i][j] = __builtin_amdgcn_mfma_f32_16x16x32_bf16(
                        af[i], bfr[j], acc[i][j], 0, 0, 0);
        }
    }

    // Epilogue: C/D layout col=lane&15, row=(lane>>4)*4+reg  [m89/m91]
    const int wr = (w >> 1) * 64, wc = (w & 1) * 64;
    const int colL = lane & 15, rowH = (lane >> 4) * 4;
    const int b = m0 >> 10;            // 128 | S, so one batch per block
    #pragma unroll
    for (int j = 0; j < 4; ++j) {
        const int col = n0 + wc + j * 16 + colL;
        const float bgv = bg[col];
        float colsum = 0.f;
        #pragma unroll
        for (int i = 0; i < 4; ++i) {
            #pragma unroll
            for (int r = 0; r < 4; ++r) {
                const int row = m0 + wr + i * 16 + rowH + r;
                const size_t off = (size_t)row * N + col;
                const float pre = acc[i][j][r] + bgv;
                const float g = 1.0f / (1.0f + __expf(-pre));
                const float gv = xf[off] * g;
                gated[off] = gv;
                colsum += gv;
            }
        }
        colsum += __shfl_xor(colsum, 16);
        colsum += __shfl_xor(colsum, 32);
        if (lane < 16)
            atomicAdd(&pooled[b * DD + col], colsum);
    }
}

// ------------------------------------------------------------------- router
// One block per b; 8 independent accumulators on the W1 dot (keep from R9).
__global__ __launch_bounds__(256) void router_kernel(
    const float* __restrict__ pooled_sum,  // [B][D] sums over S
    const float* __restrict__ W1, const float* __restrict__ b1,
    const float* __restrict__ W2, const float* __restrict__ b2,
    float* __restrict__ gains,             // [B][E]
    float* __restrict__ probs_out)         // [B][E]
{
    __shared__ float pool[DD];
    __shared__ float red[256 * EE];
    const int b = blockIdx.x, tid = threadIdx.x;

    for (int i = tid; i < DD; i += 256)
        pool[i] = pooled_sum[b * DD + i] * (1.0f / (float)SS);
    __syncthreads();

    float a0 = 0.f, a1 = 0.f, a2 = 0.f, a3 = 0.f;
    float a4 = 0.f, a5 = 0.f, a6 = 0.f, a7 = 0.f;
    for (int d = 0; d < DD; d += 8) {
        a0 = fmaf(pool[d + 0], W1[(size_t)(d + 0) * HH + tid], a0);
        a1 = fmaf(pool[d + 1], W1[(size_t)(d + 1) * HH + tid], a1);
        a2 = fmaf(pool[d + 2], W1[(size_t)(d + 2) * HH + tid], a2);
        a3 = fmaf(pool[d + 3], W1[(size_t)(d + 3) * HH + tid], a3);
        a4 = fmaf(pool[d + 4], W1[(size_t)(d + 4) * HH + tid], a4);
        a5 = fmaf(pool[d + 5], W1[(size_t)(d + 5) * HH + tid], a5);
        a6 = fmaf(pool[d + 6], W1[(size_t)(d + 6) * HH + tid], a6);
        a7 = fmaf(pool[d + 7], W1[(size_t)(d + 7) * HH + tid], a7);
    }
    const float acc = ((a0 + a1) + (a2 + a3)) + ((a4 + a5) + (a6 + a7));
    const float h = tanhf(acc + b1[tid]);

    #pragma unroll
    for (int e = 0; e < EE; ++e) red[tid * EE + e] = h * W2[tid * EE + e];
    __syncthreads();
    for (int s = 128; s > 0; s >>= 1) {
        if (tid < s) {
            #pragma unroll
            for (int e = 0; e < EE; ++e)
                red[tid * EE + e] += red[(tid + s) * EE + e];
        }
        __syncthreads();
    }

    if (tid == 0) {
        float p[EE];
        float mx = -1e30f;
        #pragma unroll
        for (int e = 0; e < EE; ++e) {
            p[e] = red[e] + b2[e];
            mx = fmaxf(mx, p[e]);
        }
        float sum = 0.f;
        #pragma unroll
        for (int e = 0; e < EE; ++e) { p[e] = __expf(p[e] - mx); sum += p[e]; }
        const float inv = 1.f / sum;
        #pragma unroll
        for (int e = 0; e < EE; ++e) { p[e] *= inv; probs_out[b * EE + e] = p[e]; }
        // top-3 (strict >, ascending scan => lowest index wins ties, matches lax.top_k)
        int   idx[3]; float tw[3];
        bool used[EE];
        #pragma unroll
        for (int e = 0; e < EE; ++e) used[e] = false;
        for (int k = 0; k < 3; ++k) {
            float best = -1.f; int bi = 0;
            for (int e = 0; e < EE; ++e)
                if (!used[e] && p[e] > best) { best = p[e]; bi = e; }
            used[bi] = true; idx[k] = bi; tw[k] = best;
        }
        const float wsum = tw[0] + tw[1] + tw[2];
        float g[EE];
        #pragma unroll
        for (int e = 0; e < EE; ++e) g[e] = 0.f;
        for (int k = 0; k < 3; ++k) g[idx[k]] = tw[k] / wsum;
        #pragma unroll
        for (int e = 0; e < EE; ++e) gains[b * EE + e] = g[e];
    }
}

// -------------------------------------------------------------- broadcast-scale v3
// out[e][b][s][d] = gains[b][e] * gated[b][s][d].
// Read-once into REGISTERS (16 f32x4/thread, static unroll), then 8 scaled
// writes as long contiguous bursts (64 KB per block per expert region slice).
// Each block's 4096-f32x4 chunk never spans a batch (4096 | 2^18) -> uniform b.
// NO nontemporal: match the 6.4 TB/s fill's write-back path; gated lines are
// read exactly once so cache pollution is harmless.
__global__ __launch_bounds__(256) void broadcast_kernel(
    const float* __restrict__ gated, const float* __restrict__ gains,
    float* __restrict__ out)
{
    const size_t n4 = (size_t)BB * SS * DD / 4;    // 4,194,304 f32x4 per expert
    const int bid = blockIdx.x;                    // 1024 blocks
    const int b   = bid >> 6;                      // 64 blocks per batch
    const size_t base = (size_t)bid * 4096 + threadIdx.x;
    const f32x4* g4 = (const f32x4*)gated;

    f32x4 v[16];
    #pragma unroll
    for (int k = 0; k < 16; ++k)
        v[k] = g4[base + (size_t)k * 256];

    f32x4* o4 = (f32x4*)out;
    #pragma unroll
    for (int e = 0; e < EE; ++e) {
        const float ge = gains[b * EE + e];
        f32x4* oe = o4 + (size_t)e * n4;
        #pragma unroll
        for (int k = 0; k < 16; ++k)
            oe[base + (size_t)k * 256] = v[k] * ge;
    }
}

// ------------------------------------------------------------------ launcher
extern "C" void kernel_launch(void* const* d_in, const int* in_sizes, int n_in,
                              void* d_out, int out_size, void* d_ws, size_t ws_size,
                              hipStream_t stream)
{
    const float* x  = (const float*)d_in[0];
    const float* Wg = (const float*)d_in[1];
    const float* bg = (const float*)d_in[2];
    const float* W1 = (const float*)d_in[3];
    const float* b1 = (const float*)d_in[4];
    const float* W2 = (const float*)d_in[5];
    const float* b2 = (const float*)d_in[6];
    float* out = (float*)d_out;

    char* ws = (char*)d_ws;
    // ws layout (bytes):
    //   [0,               33554432)   x bf16        [16384][1024]
    //   [33554432,        35651584)   WgT bf16      [1024][1024]
    //   [35651584,       102760448)   gated fp32    [16384][1024]
    //   [102760448,      102825984)   pooled fp32   [16][1024]
    //   [102825984,      102826496)   gains fp32    [16][8]
    ushort* x_bf   = (ushort*)(ws);
    ushort* WgT_bf = (ushort*)(ws + 33554432);
    float*  gated  = (float*)(ws + 35651584);
    float*  pooled = (float*)(ws + 102760448);
    float*  gains  = (float*)(ws + 102825984);

    hipMemsetAsync(pooled, 0, BB * DD * sizeof(float), stream);
    convert_x_kernel<<<2048, 256, 0, stream>>>(x, x_bf);
    transpose_wg_kernel<<<dim3(32, 32), 256, 0, stream>>>(Wg, WgT_bf);
    gemm_gate_kernel<<<1024, 256, 0, stream>>>(x_bf, WgT_bf, x, bg, gated, pooled);
    router_kernel<<<16, 256, 0, stream>>>(pooled, W1, b1, W2, b2, gains,
                                          out + (size_t)EE * BB * SS * DD);
    broadcast_kernel<<<1024, 256, 0, stream>>>(gated, gains, out);
}

// Round 11
// 704.423 us; speedup vs baseline: 1.0416x; 1.0416x over previous
//
#include <hip/hip_runtime.h>
#include <hip/hip_bf16.h>

// Problem constants (B,S,D,H,E,K = 16,1024,1024,256,8,3)
#define BB 16
#define SS 1024
#define DD 1024
#define HH 256
#define EE 8
// GEMM: M = B*S = 16384, N = D = 1024, K = D = 1024

typedef __attribute__((ext_vector_type(8))) short bf16x8;
typedef __attribute__((ext_vector_type(4))) float f32x4;

static __device__ __forceinline__ ushort f2bf(float f) {
    union { float f; unsigned u; } in;
    in.f = f;
    unsigned u = in.u;
    u += 0x7fffu + ((u >> 16) & 1u);   // round-to-nearest-even
    return (ushort)(u >> 16);
}

#define GLOAD16(gp, lp)                                                          \
    __builtin_amdgcn_global_load_lds(                                            \
        (const __attribute__((address_space(1))) void*)(gp),                     \
        (__attribute__((address_space(3))) void*)(lp), 16, 0, 0)

// --------------------------------------------- fused prep: convert x + transpose Wg
// Blocks [0,2048): x fp32 -> bf16 (vectorized). Blocks [2048,3072): Wg -> WgT bf16.
// Block-uniform divergence; saves one launch+drain vs two kernels.
__global__ __launch_bounds__(256) void prep_kernel(
    const float* __restrict__ x, ushort* __restrict__ xb,
    const float* __restrict__ Wg, ushort* __restrict__ WgT)
{
    __shared__ float tile[32][33];
    const int bid = blockIdx.x;
    if (bid < 2048) {
        const size_t n4 = (size_t)BB * SS * DD / 4;   // 4,194,304 f32x4
        const f32x4* x4 = (const f32x4*)x;
        for (size_t i = (size_t)bid * 256 + threadIdx.x; i < n4;
             i += (size_t)2048 * 256) {
            f32x4 v = x4[i];
            ushort4 o;
            o.x = f2bf(v.x); o.y = f2bf(v.y); o.z = f2bf(v.z); o.w = f2bf(v.w);
            ((ushort4*)xb)[i] = o;
        }
    } else {
        const int t  = bid - 2048;        // 0..1023
        const int bx = (t & 31) * 32;     // e base
        const int by = (t >> 5) * 32;     // d base
        const int tx = threadIdx.x & 31;
        const int ty = threadIdx.x >> 5;  // 0..7
        #pragma unroll
        for (int r = ty; r < 32; r += 8)
            tile[r][tx] = Wg[(size_t)(by + r) * DD + bx + tx];
        __syncthreads();
        #pragma unroll
        for (int r = ty; r < 32; r += 8)
            WgT[(size_t)(bx + r) * DD + by + tx] = f2bf(tile[tx][r]);
    }
}

// ------------------------------------------------------------- fused gate GEMM
// gated[m][n] = x[m][n] * sigmoid( (x_bf16 @ Wg_bf16)[m][n] + bg[n] )
// m97-style 128x128 tile, BK=64, 4 waves (2x2), 16x16x32 bf16 MFMA,
// global_load_lds width=16 staging, 2-barrier loop, XCD-chunked swizzle (T1),
// fused pooled-sum epilogue (shfl_xor reduce + atomicAdd).
// FROZEN: theory ~80-100 us; the 8-phase port is the only remaining GEMM lever.
__global__ __launch_bounds__(256) void gemm_gate_kernel(
    const ushort* __restrict__ Abf,   // x bf16 [M][K]
    const ushort* __restrict__ BTbf,  // WgT bf16 [N][K]
    const float* __restrict__ xf,     // x fp32 [M][N]  (K==N==1024)
    const float* __restrict__ bg,     // [N]
    float* __restrict__ gated,        // [M][N]
    float* __restrict__ pooled)       // [B][D] sums over S (caller memsets 0)
{
    __shared__ ushort As[128 * 64];
    __shared__ ushort Bs[128 * 64];
    const int tid  = threadIdx.x;
    const int lane = tid & 63;
    const int w    = tid >> 6;        // wave 0..3

    const int bid = blockIdx.x;                    // 1D grid of 1024
    const int swz = (bid & 7) * 128 + (bid >> 3);
    const int m0 = (swz >> 3) * 128;               // 128 m-panels
    const int n0 = (swz & 7) * 128;                // 8 n-panels
    const int K = 1024, N = 1024;

    f32x4 acc[4][4];
    #pragma unroll
    for (int i = 0; i < 4; ++i)
        #pragma unroll
        for (int j = 0; j < 4; ++j)
            acc[i][j] = (f32x4){0.f, 0.f, 0.f, 0.f};

    const int srow = (lane >> 3);      // 0..7
    const int scol = (lane & 7) * 8;   // k element offset (8 bf16 = 16B)

    for (int k0 = 0; k0 < K; k0 += 64) {
        __syncthreads();   // previous iter's LDS reads done
        #pragma unroll
        for (int c = 0; c < 4; ++c) {
            const int row = w * 32 + c * 8 + srow;
            GLOAD16(Abf + (size_t)(m0 + row) * K + k0 + scol,
                    (char*)As + w * 4096 + c * 1024 + lane * 16);
        }
        #pragma unroll
        for (int c = 0; c < 4; ++c) {
            const int row = w * 32 + c * 8 + srow;
            GLOAD16(BTbf + (size_t)(n0 + row) * K + k0 + scol,
                    (char*)Bs + w * 4096 + c * 1024 + lane * 16);
        }
        asm volatile("s_waitcnt vmcnt(0)" ::: "memory");
        __syncthreads();

        const int rbase = lane & 15;
        const int kb    = (lane >> 4) * 8;
        const int wr = (w >> 1) * 64;
        const int wc = (w & 1) * 64;
        #pragma unroll
        for (int ks = 0; ks < 2; ++ks) {
            bf16x8 af[4], bfr[4];
            #pragma unroll
            for (int i = 0; i < 4; ++i)
                af[i] = *(const bf16x8*)(As + (wr + i * 16 + rbase) * 64 + ks * 32 + kb);
            #pragma unroll
            for (int j = 0; j < 4; ++j)
                bfr[j] = *(const bf16x8*)(Bs + (wc + j * 16 + rbase) * 64 + ks * 32 + kb);
            #pragma unroll
            for (int i = 0; i < 4; ++i)
                #pragma unroll
                for (int j = 0; j < 4; ++j)
                    acc[i][j] = __builtin_amdgcn_mfma_f32_16x16x32_bf16(
                        af[i], bfr[j], acc[i][j], 0, 0, 0);
        }
    }

    // Epilogue: C/D layout col=lane&15, row=(lane>>4)*4+reg  [m89/m91]
    const int wr = (w >> 1) * 64, wc = (w & 1) * 64;
    const int colL = lane & 15, rowH = (lane >> 4) * 4;
    const int b = m0 >> 10;            // 128 | S, so one batch per block
    #pragma unroll
    for (int j = 0; j < 4; ++j) {
        const int col = n0 + wc + j * 16 + colL;
        const float bgv = bg[col];
        float colsum = 0.f;
        #pragma unroll
        for (int i = 0; i < 4; ++i) {
            #pragma unroll
            for (int r = 0; r < 4; ++r) {
                const int row = m0 + wr + i * 16 + rowH + r;
                const size_t off = (size_t)row * N + col;
                const float pre = acc[i][j][r] + bgv;
                const float g = 1.0f / (1.0f + __expf(-pre));
                const float gv = xf[off] * g;
                gated[off] = gv;
                colsum += gv;
            }
        }
        colsum += __shfl_xor(colsum, 16);
        colsum += __shfl_xor(colsum, 32);
        if (lane < 16)
            atomicAdd(&pooled[b * DD + col], colsum);
    }
}

// ------------------------------------------------------------------- router
// One block per b; 8 independent accumulators on the W1 dot (R9, keep).
__global__ __launch_bounds__(256) void router_kernel(
    const float* __restrict__ pooled_sum,  // [B][D] sums over S
    const float* __restrict__ W1, const float* __restrict__ b1,
    const float* __restrict__ W2, const float* __restrict__ b2,
    float* __restrict__ gains,             // [B][E]
    float* __restrict__ probs_out)         // [B][E]
{
    __shared__ float pool[DD];
    __shared__ float red[256 * EE];
    const int b = blockIdx.x, tid = threadIdx.x;

    for (int i = tid; i < DD; i += 256)
        pool[i] = pooled_sum[b * DD + i] * (1.0f / (float)SS);
    __syncthreads();

    float a0 = 0.f, a1 = 0.f, a2 = 0.f, a3 = 0.f;
    float a4 = 0.f, a5 = 0.f, a6 = 0.f, a7 = 0.f;
    for (int d = 0; d < DD; d += 8) {
        a0 = fmaf(pool[d + 0], W1[(size_t)(d + 0) * HH + tid], a0);
        a1 = fmaf(pool[d + 1], W1[(size_t)(d + 1) * HH + tid], a1);
        a2 = fmaf(pool[d + 2], W1[(size_t)(d + 2) * HH + tid], a2);
        a3 = fmaf(pool[d + 3], W1[(size_t)(d + 3) * HH + tid], a3);
        a4 = fmaf(pool[d + 4], W1[(size_t)(d + 4) * HH + tid], a4);
        a5 = fmaf(pool[d + 5], W1[(size_t)(d + 5) * HH + tid], a5);
        a6 = fmaf(pool[d + 6], W1[(size_t)(d + 6) * HH + tid], a6);
        a7 = fmaf(pool[d + 7], W1[(size_t)(d + 7) * HH + tid], a7);
    }
    const float acc = ((a0 + a1) + (a2 + a3)) + ((a4 + a5) + (a6 + a7));
    const float h = tanhf(acc + b1[tid]);

    #pragma unroll
    for (int e = 0; e < EE; ++e) red[tid * EE + e] = h * W2[tid * EE + e];
    __syncthreads();
    for (int s = 128; s > 0; s >>= 1) {
        if (tid < s) {
            #pragma unroll
            for (int e = 0; e < EE; ++e)
                red[tid * EE + e] += red[(tid + s) * EE + e];
        }
        __syncthreads();
    }

    if (tid == 0) {
        float p[EE];
        float mx = -1e30f;
        #pragma unroll
        for (int e = 0; e < EE; ++e) {
            p[e] = red[e] + b2[e];
            mx = fmaxf(mx, p[e]);
        }
        float sum = 0.f;
        #pragma unroll
        for (int e = 0; e < EE; ++e) { p[e] = __expf(p[e] - mx); sum += p[e]; }
        const float inv = 1.f / sum;
        #pragma unroll
        for (int e = 0; e < EE; ++e) { p[e] *= inv; probs_out[b * EE + e] = p[e]; }
        // top-3 (strict >, ascending scan => lowest index wins ties, matches lax.top_k)
        int   idx[3]; float tw[3];
        bool used[EE];
        #pragma unroll
        for (int e = 0; e < EE; ++e) used[e] = false;
        for (int k = 0; k < 3; ++k) {
            float best = -1.f; int bi = 0;
            for (int e = 0; e < EE; ++e)
                if (!used[e] && p[e] > best) { best = p[e]; bi = e; }
            used[bi] = true; idx[k] = bi; tw[k] = best;
        }
        const float wsum = tw[0] + tw[1] + tw[2];
        float g[EE];
        #pragma unroll
        for (int e = 0; e < EE; ++e) g[e] = 0.f;
        for (int k = 0; k < 3; ++k) g[idx[k]] = tw[k] / wsum;
        #pragma unroll
        for (int e = 0; e < EE; ++e) gains[b * EE + e] = g[e];
    }
}

// -------------------------------------------------------------- broadcast-scale
// REVERTED to the round-7 v1 form — best measured total (706 vs 715/734 for
// v2/v3). Per-thread read-once, 8 NT stores (one per expert stream).
__global__ __launch_bounds__(256) void broadcast_kernel(
    const float* __restrict__ gated, const float* __restrict__ gains,
    float* __restrict__ out)
{
    const size_t n4 = (size_t)BB * SS * DD / 4;       // 4,194,304 f32x4
    const size_t e_stride = n4;                        // f32x4 stride per expert
    const f32x4* g4 = (const f32x4*)gated;
    f32x4* o4 = (f32x4*)out;
    for (size_t i = (size_t)blockIdx.x * 256 + threadIdx.x; i < n4;
         i += (size_t)gridDim.x * 256) {
        const int b = (int)(i >> 18);                  // SS*DD/4 = 2^18 per b
        const f32x4 v = g4[i];
        const float* gb = gains + b * EE;
        #pragma unroll
        for (int e = 0; e < EE; ++e) {
            const float ge = gb[e];
            f32x4 r = v * ge;
            __builtin_nontemporal_store(r, &o4[(size_t)e * e_stride + i]);
        }
    }
}

// ------------------------------------------------------------------ launcher
extern "C" void kernel_launch(void* const* d_in, const int* in_sizes, int n_in,
                              void* d_out, int out_size, void* d_ws, size_t ws_size,
                              hipStream_t stream)
{
    const float* x  = (const float*)d_in[0];
    const float* Wg = (const float*)d_in[1];
    const float* bg = (const float*)d_in[2];
    const float* W1 = (const float*)d_in[3];
    const float* b1 = (const float*)d_in[4];
    const float* W2 = (const float*)d_in[5];
    const float* b2 = (const float*)d_in[6];
    float* out = (float*)d_out;

    char* ws = (char*)d_ws;
    // ws layout (bytes):
    //   [0,               33554432)   x bf16        [16384][1024]
    //   [33554432,        35651584)   WgT bf16      [1024][1024]
    //   [35651584,       102760448)   gated fp32    [16384][1024]
    //   [102760448,      102825984)   pooled fp32   [16][1024]
    //   [102825984,      102826496)   gains fp32    [16][8]
    ushort* x_bf   = (ushort*)(ws);
    ushort* WgT_bf = (ushort*)(ws + 33554432);
    float*  gated  = (float*)(ws + 35651584);
    float*  pooled = (float*)(ws + 102760448);
    float*  gains  = (float*)(ws + 102825984);

    hipMemsetAsync(pooled, 0, BB * DD * sizeof(float), stream);
    prep_kernel<<<3072, 256, 0, stream>>>(x, x_bf, Wg, WgT_bf);
    gemm_gate_kernel<<<1024, 256, 0, stream>>>(x_bf, WgT_bf, x, bg, gated, pooled);
    router_kernel<<<16, 256, 0, stream>>>(pooled, W1, b1, W2, b2, gains,
                                          out + (size_t)EE * BB * SS * DD);
    broadcast_kernel<<<2048, 256, 0, stream>>>(gated, gains, out);
}